// Round 11
// baseline (46.058 us; speedup 1.0000x reference)
//
#include <hip/hip_runtime.h>

#define DS   256
#define FULL 2048
#define NIMG 8
#define CG   4      // columns per k_colup block

typedef float f32x4 __attribute__((ext_vector_type(4)));
typedef int   i32x4 __attribute__((ext_vector_type(4)));

// Segment-mean contribution for a 256-long line handled by 256 threads.
// Returns lr+rl (or 2x where invalid), matching the reference _seg_means.
// Safe to call back-to-back (internal barriers cover the reuse hazards).
__device__ __forceinline__ float seg_fast(float x, bool z, int j,
                                          float* s_cs,
                                          unsigned long long* s_msk,
                                          float* s_ws) {
    const int lane = j & 63;
    const int w    = j >> 6;
    unsigned long long m = __ballot(z);

    float s = x;
    #pragma unroll
    for (int off = 1; off < 64; off <<= 1) {
        float t = __shfl_up(s, off, 64);
        if (lane >= off) s += t;
    }
    if (lane == 63) s_ws[w]  = s;
    if (lane == 0)  s_msk[w] = m;
    __syncthreads();

    float pre = 0.f;
    for (int ww = 0; ww < w; ++ww) pre += s_ws[ww];
    s += pre;
    s_cs[j] = s;

    unsigned long long lo = m & ((1ULL << lane) - 1ULL);
    int prev = -1;
    if (lo) prev = (w << 6) + 63 - __builtin_clzll(lo);
    else {
        for (int ww = w - 1; ww >= 0; --ww) {
            unsigned long long mm = s_msk[ww];
            if (mm) { prev = (ww << 6) + 63 - __builtin_clzll(mm); break; }
        }
    }
    unsigned long long hi = m & ~((2ULL << lane) - 1ULL);
    int nxt = DS;
    if (hi) nxt = (w << 6) + __builtin_ctzll(hi);
    else {
        for (int ww = w + 1; ww < 4; ++ww) {
            unsigned long long mm = s_msk[ww];
            if (mm) { nxt = (ww << 6) + __builtin_ctzll(mm); break; }
        }
    }
    __syncthreads();   // s_cs fully written

    bool valid = (!z) && (prev >= 0) && (nxt < DS);
    if (valid) {
        float cs_j   = s_cs[j];
        float cs_pm1 = (prev > 0) ? s_cs[prev - 1] : 0.f;
        float cs_n   = s_cs[nxt];
        float cs_jm1 = (j > 0) ? s_cs[j - 1] : 0.f;
        return (cs_j - cs_pm1) / (float)(j - prev + 1)
             + (cs_n - cs_jm1) / (float)(nxt - j + 1);
    }
    return 2.f * x;
}

// K_A: one downsampled row per block. Thread j loads the 16B chunk that
// CONTAINS sample j (byte 32j, elem 0) -> 2 loads/thread, no LDS exchange.
__global__ __launch_bounds__(256) void k_row(const float* __restrict__ x0,
                                             const int* __restrict__ x1,
                                             float2* __restrict__ xz,
                                             float* __restrict__ yH) {
    __shared__ float s_cs[DS];
    __shared__ unsigned long long s_msk[4];
    __shared__ float s_ws[4];
    const int j = threadIdx.x;
    const int line = blockIdx.x;            // n*256 + i
    const int n = line >> 8, i = line & 255;

    const float* rb0 = x0 + (size_t)(n * FULL + i * 8) * FULL;
    const int*   rb1 = x1 + (size_t)(n * FULL + i * 8) * FULL;
    f32x4 a = __builtin_nontemporal_load((const f32x4*)(rb0 + 8 * (size_t)j));
    i32x4 b = __builtin_nontemporal_load((const i32x4*)(rb1 + 8 * (size_t)j));
    float x = a[0];
    bool  z = (b[0] == 0);

    float r = seg_fast(x, z, j, s_cs, s_msk, s_ws);

    yH[(line << 8) + j] = r;                              // coalesced
    xz[(line << 8) + j] = make_float2(x, z ? 1.f : 0.f);  // coalesced
}

// K_B: (image, colgroup, row-quarter) per block — 2048 blocks (8/CU).
// The 4 row-quarter blocks redundantly run the cheap 4-column scans; each
// writes only its quarter of the upsampled rows (4x write concurrency).
__global__ __launch_bounds__(256) void k_colup(const float2* __restrict__ xz,
                                               const float* __restrict__ yH,
                                               f32x4* __restrict__ out) {
    __shared__ float s_x[CG][DS];
    __shared__ float s_z[CG][DS];
    __shared__ float s_out[CG][DS + 1];      // +1 pad: conflict-free col reads
    __shared__ float s_cs[DS];
    __shared__ unsigned long long s_msk[4];
    __shared__ float s_ws[4];
    const int t = threadIdx.x;               // downsampled row
    const int g = blockIdx.x;                // n*256 + quarter*64 + colgroup
    const int n  = g >> 8;
    const int q  = (g >> 6) & 3;             // which quarter of output rows
    const int c0 = (g & 63) * CG;

    // issue all 3 global loads up front (cover L2/L3 latency)
    const float2* base = xz + (n << 16) + (t << 8) + c0;
    f32x4 v0 = *(const f32x4*)(base);        // (x,z) for c0, c0+1
    f32x4 v1 = *(const f32x4*)(base + 2);    // (x,z) for c0+2, c0+3
    f32x4 h  = *(const f32x4*)(yH + (n << 16) + (t << 8) + c0);
    s_x[0][t] = v0[0]; s_z[0][t] = v0[1];
    s_x[1][t] = v0[2]; s_z[1][t] = v0[3];
    s_x[2][t] = v1[0]; s_z[2][t] = v1[1];
    s_x[3][t] = v1[2]; s_z[3][t] = v1[3];
    // no barrier needed: each thread reads back only its own s_x/s_z entries.

    #pragma unroll
    for (int c = 0; c < CG; ++c) {
        float x = s_x[c][t];
        bool  z = (s_z[c][t] != 0.f);
        float r = seg_fast(x, z, t, s_cs, s_msk, s_ws);
        s_out[c][t] = r + h[c];              // vertical + horizontal
    }
    __syncthreads();                         // s_out complete

    // This block's quarter: 512 output rows x 8 f32x4 slots (32 cols).
    // Each thread: two consecutive f32x4 (32B) per iteration, plain stores.
    f32x4* ob = out + ((size_t)n << 20) + (c0 << 1);
    #pragma unroll 4
    for (int k = 0; k < 8; ++k) {
        int idx = (k << 8) + t;              // 0..2047 (pair index)
        int I   = (q << 9) + (idx >> 2);     // output row
        int c   = idx & 3;                   // downsampled column within group
        float v = s_out[c][I >> 3];
        f32x4 vv = { v, v, v, v };
        size_t o = (size_t)I * 512 + (c << 1);
        ob[o]     = vv;
        ob[o + 1] = vv;
    }
}

extern "C" void kernel_launch(void* const* d_in, const int* in_sizes, int n_in,
                              void* d_out, int out_size, void* d_ws, size_t ws_size,
                              hipStream_t stream) {
    const float* x0 = (const float*)d_in[0];
    const int*   x1 = (const int*)d_in[1];
    f32x4* out = (f32x4*)d_out;

    // ws layout: xz (4MB float2) | yH (2MB)
    float2* xz = (float2*)d_ws;
    float*  yH = (float*)(xz + NIMG * DS * DS);

    dim3 blk(256);
    k_row  <<<dim3(NIMG * DS),          blk, 0, stream>>>(x0, x1, xz, yH);
    k_colup<<<dim3(4 * NIMG * DS / CG), blk, 0, stream>>>(xz, yH, out);
}

// Round 13
// 45.154 us; speedup vs baseline: 1.0200x; 1.0200x over previous
//
#include <hip/hip_runtime.h>

#define DS   256
#define FULL 2048
#define NIMG 8
#define CG   8      // ds-columns per k_colup block

typedef float f32x4 __attribute__((ext_vector_type(4)));
typedef int   i32x4 __attribute__((ext_vector_type(4)));

// Segment-mean contribution for a 256-long line handled by 256 threads.
// Returns lr+rl (or 2x where invalid), matching the reference _seg_means.
// Safe to call back-to-back (internal barriers cover the reuse hazards).
__device__ __forceinline__ float seg_fast(float x, bool z, int j,
                                          float* s_cs,
                                          unsigned long long* s_msk,
                                          float* s_ws) {
    const int lane = j & 63;
    const int w    = j >> 6;
    unsigned long long m = __ballot(z);

    float s = x;
    #pragma unroll
    for (int off = 1; off < 64; off <<= 1) {
        float t = __shfl_up(s, off, 64);
        if (lane >= off) s += t;
    }
    if (lane == 63) s_ws[w]  = s;
    if (lane == 0)  s_msk[w] = m;
    __syncthreads();

    float pre = 0.f;
    for (int ww = 0; ww < w; ++ww) pre += s_ws[ww];
    s += pre;
    s_cs[j] = s;

    unsigned long long lo = m & ((1ULL << lane) - 1ULL);
    int prev = -1;
    if (lo) prev = (w << 6) + 63 - __builtin_clzll(lo);
    else {
        for (int ww = w - 1; ww >= 0; --ww) {
            unsigned long long mm = s_msk[ww];
            if (mm) { prev = (ww << 6) + 63 - __builtin_clzll(mm); break; }
        }
    }
    unsigned long long hi = m & ~((2ULL << lane) - 1ULL);
    int nxt = DS;
    if (hi) nxt = (w << 6) + __builtin_ctzll(hi);
    else {
        for (int ww = w + 1; ww < 4; ++ww) {
            unsigned long long mm = s_msk[ww];
            if (mm) { nxt = (ww << 6) + __builtin_ctzll(mm); break; }
        }
    }
    __syncthreads();   // s_cs fully written

    bool valid = (!z) && (prev >= 0) && (nxt < DS);
    if (valid) {
        float cs_j   = s_cs[j];
        float cs_pm1 = (prev > 0) ? s_cs[prev - 1] : 0.f;
        float cs_n   = s_cs[nxt];
        float cs_jm1 = (j > 0) ? s_cs[j - 1] : 0.f;
        return (cs_j - cs_pm1) / (float)(j - prev + 1)
             + (cs_n - cs_jm1) / (float)(nxt - j + 1);
    }
    return 2.f * x;
}

// K_A: one downsampled row per block. Thread j loads the 16B chunk that
// CONTAINS sample j (byte 32j, elem 0) -> 2 loads/thread, no LDS exchange.
__global__ __launch_bounds__(256) void k_row(const float* __restrict__ x0,
                                             const int* __restrict__ x1,
                                             float2* __restrict__ xz,
                                             float* __restrict__ yH) {
    __shared__ float s_cs[DS];
    __shared__ unsigned long long s_msk[4];
    __shared__ float s_ws[4];
    const int j = threadIdx.x;
    const int line = blockIdx.x;            // n*256 + i
    const int n = line >> 8, i = line & 255;

    const float* rb0 = x0 + (size_t)(n * FULL + i * 8) * FULL;
    const int*   rb1 = x1 + (size_t)(n * FULL + i * 8) * FULL;
    f32x4 a = __builtin_nontemporal_load((const f32x4*)(rb0 + 8 * (size_t)j));
    i32x4 b = __builtin_nontemporal_load((const i32x4*)(rb1 + 8 * (size_t)j));
    float x = a[0];
    bool  z = (b[0] == 0);

    float r = seg_fast(x, z, j, s_cs, s_msk, s_ws);

    yH[(line << 8) + j] = r;                              // coalesced
    xz[(line << 8) + j] = make_float2(x, z ? 1.f : 0.f);  // coalesced
}

// K_B: (image, 8-col group, row-quarter) per block — 1024 blocks.
// The 4 row-quarter replicas run identical 8-column scans (inputs in
// REGISTERS, no LDS staging); each writes its quarter of the upsampled
// rows: 512 rows x 256B contiguous per row (2x page locality vs CG=4).
__global__ __launch_bounds__(256) void k_colup(const float2* __restrict__ xz,
                                               const float* __restrict__ yH,
                                               f32x4* __restrict__ out) {
    __shared__ float s_out[CG][DS + 1];      // +1 pad
    __shared__ float s_cs[DS];
    __shared__ unsigned long long s_msk[4];
    __shared__ float s_ws[4];
    const int t = threadIdx.x;               // downsampled row
    const int g = blockIdx.x;                // n*128 + quarter*32 + colgroup
    const int n  = g >> 7;
    const int q  = (g >> 5) & 3;             // row quarter
    const int c0 = (g & 31) << 3;            // first ds column

    // issue all global loads up front (cover latency)
    const float2* base = xz + (n << 16) + (t << 8) + c0;
    f32x4 v0 = *(const f32x4*)(base);
    f32x4 v1 = *(const f32x4*)(base + 2);
    f32x4 v2 = *(const f32x4*)(base + 4);
    f32x4 v3 = *(const f32x4*)(base + 6);
    const float* hb = yH + (n << 16) + (t << 8) + c0;
    f32x4 h0 = *(const f32x4*)(hb);
    f32x4 h1 = *(const f32x4*)(hb + 4);

    float xa[CG] = { v0[0], v0[2], v1[0], v1[2], v2[0], v2[2], v3[0], v3[2] };
    float za[CG] = { v0[1], v0[3], v1[1], v1[3], v2[1], v2[3], v3[1], v3[3] };
    float ha[CG] = { h0[0], h0[1], h0[2], h0[3], h1[0], h1[1], h1[2], h1[3] };

    #pragma unroll
    for (int c = 0; c < CG; ++c) {
        float r = seg_fast(xa[c], za[c] != 0.f, t, s_cs, s_msk, s_ws);
        s_out[c][t] = r + ha[c];             // vertical + horizontal
    }
    __syncthreads();                         // s_out complete

    // This block's quarter: 512 output rows x 16 f32x4 slots (64 cols)
    // = 4096 store-pairs. Each thread: two consecutive f32x4 (32B) per
    // iteration, plain stores.
    f32x4* ob = out + ((size_t)n << 20);
    #pragma unroll
    for (int k = 0; k < 16; ++k) {
        int idx = (k << 8) + t;              // 0..4095 (pair index)
        int I   = (q << 9) + (idx >> 3);     // output row (512 per quarter)
        int p   = idx & 7;                   // ds column within group
        float v = s_out[p][I >> 3];
        f32x4 vv = { v, v, v, v };
        size_t o = (size_t)I * 512 + ((c0 + p) << 1);
        ob[o]     = vv;
        ob[o + 1] = vv;
    }
}

extern "C" void kernel_launch(void* const* d_in, const int* in_sizes, int n_in,
                              void* d_out, int out_size, void* d_ws, size_t ws_size,
                              hipStream_t stream) {
    const float* x0 = (const float*)d_in[0];
    const int*   x1 = (const int*)d_in[1];
    f32x4* out = (f32x4*)d_out;

    // ws layout: xz (4MB float2) | yH (2MB)
    float2* xz = (float2*)d_ws;
    float*  yH = (float*)(xz + NIMG * DS * DS);

    dim3 blk(256);
    k_row  <<<dim3(NIMG * DS),              blk, 0, stream>>>(x0, x1, xz, yH);
    k_colup<<<dim3(NIMG * (DS / CG) * 4),   blk, 0, stream>>>(xz, yH, out);
}

// Round 14
// 44.454 us; speedup vs baseline: 1.0361x; 1.0158x over previous
//
#include <hip/hip_runtime.h>

#define DS   256
#define FULL 2048
#define NIMG 8
#define CG   4      // ds-columns per k_colup block

typedef float f32x4 __attribute__((ext_vector_type(4)));
typedef int   i32x4 __attribute__((ext_vector_type(4)));

// Segment-mean contribution for a 256-long line handled by 256 threads.
// Returns lr+rl (or 2x where invalid), matching the reference _seg_means.
// Safe to call back-to-back (barriers cover all cross-call reuse hazards).
__device__ __forceinline__ float seg_fast(float x, bool z, int j,
                                          float* s_cs,
                                          unsigned long long* s_msk,
                                          float* s_ws) {
    const int lane = j & 63;
    const int w    = j >> 6;
    unsigned long long m = __ballot(z);

    float s = x;
    #pragma unroll
    for (int off = 1; off < 64; off <<= 1) {
        float t = __shfl_up(s, off, 64);
        if (lane >= off) s += t;
    }
    if (lane == 63) s_ws[w]  = s;
    if (lane == 0)  s_msk[w] = m;
    __syncthreads();

    float pre = 0.f;
    for (int ww = 0; ww < w; ++ww) pre += s_ws[ww];
    s += pre;
    s_cs[j] = s;

    unsigned long long lo = m & ((1ULL << lane) - 1ULL);
    int prev = -1;
    if (lo) prev = (w << 6) + 63 - __builtin_clzll(lo);
    else {
        for (int ww = w - 1; ww >= 0; --ww) {
            unsigned long long mm = s_msk[ww];
            if (mm) { prev = (ww << 6) + 63 - __builtin_clzll(mm); break; }
        }
    }
    unsigned long long hi = m & ~((2ULL << lane) - 1ULL);
    int nxt = DS;
    if (hi) nxt = (w << 6) + __builtin_ctzll(hi);
    else {
        for (int ww = w + 1; ww < 4; ++ww) {
            unsigned long long mm = s_msk[ww];
            if (mm) { nxt = (ww << 6) + __builtin_ctzll(mm); break; }
        }
    }
    __syncthreads();   // s_cs fully written

    bool valid = (!z) && (prev >= 0) && (nxt < DS);
    if (valid) {
        float cs_j   = s_cs[j];
        float cs_pm1 = (prev > 0) ? s_cs[prev - 1] : 0.f;
        float cs_n   = s_cs[nxt];
        float cs_jm1 = (j > 0) ? s_cs[j - 1] : 0.f;
        return (cs_j - cs_pm1) / (float)(j - prev + 1)
             + (cs_n - cs_jm1) / (float)(nxt - j + 1);
    }
    return 2.f * x;
}

// K_A: TWO downsampled rows per block (1024 blocks). Thread j issues all 4
// 16B loads up front (both rows' x0/x1 chunks containing sample j), then
// runs two scans. Same HBM lines touched; 2x MLP, half the launch chains.
__global__ __launch_bounds__(256) void k_row(const float* __restrict__ x0,
                                             const int* __restrict__ x1,
                                             float2* __restrict__ xz,
                                             float* __restrict__ yH) {
    __shared__ float s_cs[DS];
    __shared__ unsigned long long s_msk[4];
    __shared__ float s_ws[4];
    const int j = threadIdx.x;
    const int line0 = blockIdx.x << 1;      // first of 2 lines: n*256 + i
    const int n = line0 >> 8, i0 = line0 & 255;

    const float* rb0 = x0 + (size_t)(n * FULL + i0 * 8) * FULL;
    const int*   rb1 = x1 + (size_t)(n * FULL + i0 * 8) * FULL;
    // 4 independent loads in flight (rows i0 and i0+1; +8 full rows = 16384 floats)
    f32x4 a0 = __builtin_nontemporal_load((const f32x4*)(rb0 + 8 * (size_t)j));
    i32x4 b0 = __builtin_nontemporal_load((const i32x4*)(rb1 + 8 * (size_t)j));
    f32x4 a1 = __builtin_nontemporal_load((const f32x4*)(rb0 + 16384 + 8 * (size_t)j));
    i32x4 b1 = __builtin_nontemporal_load((const i32x4*)(rb1 + 16384 + 8 * (size_t)j));

    float x = a0[0];
    bool  z = (b0[0] == 0);
    float r = seg_fast(x, z, j, s_cs, s_msk, s_ws);
    yH[(line0 << 8) + j] = r;
    xz[(line0 << 8) + j] = make_float2(x, z ? 1.f : 0.f);

    x = a1[0];
    z = (b1[0] == 0);
    r = seg_fast(x, z, j, s_cs, s_msk, s_ws);
    yH[((line0 + 1) << 8) + j] = r;
    xz[((line0 + 1) << 8) + j] = make_float2(x, z ? 1.f : 0.f);
}

// K_B: (image, 4-col group, row-half) per block — 1024 blocks (R10 geometry,
// the measured best). Scan inputs held in REGISTERS (no s_x/s_z round-trip).
// Write pattern byte-identical to R10: 1024 rows x 128B segments, plain
// stores, 32B contiguous per thread.
__global__ __launch_bounds__(256) void k_colup(const float2* __restrict__ xz,
                                               const float* __restrict__ yH,
                                               f32x4* __restrict__ out) {
    __shared__ float s_out[CG][DS + 1];      // +1 pad
    __shared__ float s_cs[DS];
    __shared__ unsigned long long s_msk[4];
    __shared__ float s_ws[4];
    const int t = threadIdx.x;               // downsampled row
    const int g = blockIdx.x;                // n*128 + rowhalf*64 + colgroup
    const int n  = g >> 7;
    const int q  = (g >> 6) & 1;             // which half of output rows
    const int c0 = (g & 63) * CG;

    // 3 loads issued up front (cover L2/L3 latency)
    const float2* base = xz + (n << 16) + (t << 8) + c0;
    f32x4 v0 = *(const f32x4*)(base);        // (x,z) for c0, c0+1
    f32x4 v1 = *(const f32x4*)(base + 2);    // (x,z) for c0+2, c0+3
    f32x4 h  = *(const f32x4*)(yH + (n << 16) + (t << 8) + c0);

    float xa[CG] = { v0[0], v0[2], v1[0], v1[2] };
    float za[CG] = { v0[1], v0[3], v1[1], v1[3] };

    #pragma unroll
    for (int c = 0; c < CG; ++c) {
        float r = seg_fast(xa[c], za[c] != 0.f, t, s_cs, s_msk, s_ws);
        s_out[c][t] = r + h[c];              // vertical + horizontal
    }
    __syncthreads();                         // s_out complete

    // This block's half: 1024 output rows x 8 f32x4 slots (32 cols).
    f32x4* ob = out + ((size_t)n << 20) + (c0 << 1);
    #pragma unroll 4
    for (int k = 0; k < 16; ++k) {
        int idx = (k << 8) + t;              // 0..4095 (pair index)
        int I   = (q << 10) + (idx >> 2);    // output row
        int c   = idx & 3;                   // ds column within group
        float v = s_out[c][I >> 3];
        f32x4 vv = { v, v, v, v };
        size_t o = (size_t)I * 512 + (c << 1);
        ob[o]     = vv;
        ob[o + 1] = vv;
    }
}

extern "C" void kernel_launch(void* const* d_in, const int* in_sizes, int n_in,
                              void* d_out, int out_size, void* d_ws, size_t ws_size,
                              hipStream_t stream) {
    const float* x0 = (const float*)d_in[0];
    const int*   x1 = (const int*)d_in[1];
    f32x4* out = (f32x4*)d_out;

    // ws layout: xz (4MB float2) | yH (2MB)
    float2* xz = (float2*)d_ws;
    float*  yH = (float*)(xz + NIMG * DS * DS);

    dim3 blk(256);
    k_row  <<<dim3(NIMG * DS / 2),      blk, 0, stream>>>(x0, x1, xz, yH);
    k_colup<<<dim3(2 * NIMG * DS / CG), blk, 0, stream>>>(xz, yH, out);
}